// Round 16
// baseline (201.880 us; speedup 1.0000x reference)
//
#include <hip/hip_runtime.h>
#include <hip/hip_bf16.h>
#include <stdint.h>

#define TSTEPS 500
#define BB 32
#define N0 512
#define N1 1024
#define N2 512

typedef unsigned short ushort_t;
typedef __attribute__((ext_vector_type(8))) short short8;
typedef __attribute__((ext_vector_type(4))) float f32x4;

// ---------------- bf16 helpers --------------------------------------------
__device__ __forceinline__ ushort_t f2b(float x) {
    union { float f; uint32_t u; } c; c.f = x;
    uint32_t r = (c.u + 0x7fffu + ((c.u >> 16) & 1u)) >> 16;
    return (ushort_t)r;
}
__device__ __forceinline__ float b2f(ushort_t u) {
    union { uint32_t u; float f; } c; c.u = ((uint32_t)u) << 16;
    return c.f;
}

// ---------------- GLIFR step, algebraically reduced ------------------------
__device__ __forceinline__ float glifr_step(float& v, float& a0, float& a1,
                                            float x) {
    const float INV_I0 = 1.0f / 700.0f;
    const float C2 = 9.43f / 700.0f;
    const float CE = 0.14426950408889634f;
    const float CE10 = 1.4426950408889634f;
    const float C0 = 1.0f - 0.05f * 0.003f;
    const float C1 = 1.0f - 0.05f * 0.1f;
    const float AMP0 = -9.18f, AMP1 = -198.94f;

    float asum = a0 + a1;
    float drv = fmaf(asum, INV_I0, x);
    float e = exp2f(fmaf(v, -CE, CE10));
    float sig = __builtin_amdgcn_rcpf(1.0f + e);
    float na0 = fmaf(sig, a0 + AMP0, a0 * C0);
    float na1 = fmaf(sig, a1 + AMP1, a1 * C1);
    float nv = fmaf(-sig, v, fmaf(-C2, v, v + drv));
    a0 = na0; a1 = na1; v = nv;
    return sig;
}

// ---------------- scan body: round-9 proven rolling PD=25 prefetch ---------
#define PD 25
template <int NW, int MODE>
__device__ __forceinline__ void scan_body(const float* __restrict__ drive,
                                          uint32_t* __restrict__ pout,
                                          float* __restrict__ fout, int idx) {
    const int S = BB * NW;

    auto LD = [&](int t) -> float {
        if (MODE == 0) return drive[(size_t)t * S + idx];
        return (t == 0) ? 0.0f : drive[(size_t)(t - 1) * S + idx];
    };

    float v = 0.f, a0 = 0.f, a1 = 0.f;

    auto STEP = [&](int t, float x) {
        float sig = glifr_step(v, a0, a1, x);
        size_t o = (size_t)t * S + idx;
        if (MODE == 2) {
            fout[o] = 20.0f * sig;
        } else {
            uint32_t su = __float_as_uint(sig);
            float lo = sig - __uint_as_float(su & 0xffff0000u);
            pout[o] = (su >> 16) | (__float_as_uint(lo) & 0xffff0000u);
        }
    };

    float p[PD];
#pragma unroll
    for (int i = 0; i < PD; ++i) p[i] = LD(i);

    for (int t = 0; t < TSTEPS - PD; t += PD) {
        float q[PD];
#pragma unroll
        for (int i = 0; i < PD; ++i) q[i] = LD(t + PD + i);
#pragma unroll
        for (int i = 0; i < PD; ++i) STEP(t + i, p[i]);
#pragma unroll
        for (int i = 0; i < PD; ++i) p[i] = q[i];
    }
#pragma unroll
    for (int i = 0; i < PD; ++i) STEP(TSTEPS - PD + i, p[i]);
}

// ---------------- scan0 fused with weight split ----------------------------
__global__ __launch_bounds__(64, 1) void scan0_wsplit(
    const float* __restrict__ inputs, uint32_t* __restrict__ s0,
    const float* __restrict__ W1, const float* __restrict__ W2,
    ushort_t* __restrict__ w1h, ushort_t* __restrict__ w1l,
    ushort_t* __restrict__ w2h, ushort_t* __restrict__ w2l) {
    const int bid = blockIdx.x;
    if (bid < (BB * N0) / 64) {
        scan_body<N0, 0>(inputs, s0, nullptr, bid * 64 + threadIdx.x);
    } else {
        int i = (bid - (BB * N0) / 64) * 64 + threadIdx.x;
        float a = 20.0f * W1[i];
        ushort_t h = f2b(a);
        w1h[i] = h; w1l[i] = f2b(a - b2f(h));
        float b = 20.0f * W2[i];
        h = f2b(b);
        w2h[i] = h; w2l[i] = f2b(b - b2f(h));
    }
}

template <int NW>
__global__ __launch_bounds__(64, 1) void scan_mid(
    const float* __restrict__ drive, uint32_t* __restrict__ sout) {
    scan_body<NW, 1>(drive, sout, nullptr,
                     blockIdx.x * blockDim.x + threadIdx.x);
}

__global__ __launch_bounds__(64, 1) void scan_last(
    const float* __restrict__ drive, float* __restrict__ out) {
    scan_body<N2, 2>(drive, nullptr, out,
                     blockIdx.x * blockDim.x + threadIdx.x);
}

// ---------------- bf16x3-split MFMA GEMM, 8-wave repartition ---------------
// Same algorithm/LDS layout/pipeline as round 9, re-partitioned onto 512
// threads: wave-tile 64x32 (wm=wave>>2, wn=wave&3), acc 32 VGPR/wave ->
// __launch_bounds__(512,4) caps at 128 VGPR (no r8-style spill), LDS 80KB
// unchanged -> 2 blocks/CU -> 16 waves/CU = 4/SIMD (2x latency hiding).
template <int NBY, int KC>
__global__ __launch_bounds__(512, 4) void gemm_x3(
    const uint32_t* __restrict__ Apk,
    const ushort_t* __restrict__ Bh, const ushort_t* __restrict__ Bl,
    float* __restrict__ C) {
    constexpr int NC = NBY * 128;
    constexpr int KSTEPS = KC / 32;   // 16 or 32 (even)
    __shared__ char lds[81920];       // A: 2x16KB @0 ; B: 3x16KB @32768
    const int tid = threadIdx.x;
    const int lane = tid & 63, wave = tid >> 6;   // wave 0..7

    // bijective XCD swizzle (m204)
    const int id = blockIdx.x, nwg = gridDim.x;
    const int qq = nwg >> 3, rr = nwg & 7;
    const int xcd = id & 7, jj = id >> 3;
    const int wg = (xcd < rr ? xcd * (qq + 1) : rr * (qq + 1) + (xcd - rr) * qq) + jj;
    const int m0 = (wg / NBY) * 128;
    const int n0 = (wg % NBY) * 128;

    // B staging (waves 4..7): plane = (wave>>1)&1 (0=Bh,1=Bl), rowhalf = wave&1
    const int bplane = (wave >> 1) & 1, brhalf = wave & 1;
    const ushort_t* gB = bplane ? Bl : Bh;
    const int chunk_sw = (lane & 3) ^ ((lane >> 3) & 3);
    const size_t rowbB = (size_t)KC * 2;
    const char* gsrcB = (const char*)gB +
                        (size_t)(n0 + brhalf * 64 + (lane >> 2)) * rowbB +
                        (size_t)chunk_sw * 16;
    const int bDst = 32768 + bplane * 8192 + brhalf * 4096;  // + bbuf*16384 + i*1024

    // A staging (all 512 threads): rows r0, r0+64; 2 x uint4 per K-tile
    const int r0 = tid >> 3, c4 = tid & 7;          // r0 0..63, chunk 0..7
    const int ch = (c4 >> 1) ^ ((r0 >> 1) & 3);     // swizzled 16B slot
    const int aoff = r0 * 64 + ch * 16 + (c4 & 1) * 8;
    const uint32_t* aSrc = Apk + (size_t)(m0 + r0) * KC + c4 * 4;

    const int wm = wave >> 2, wn = wave & 3;        // 64-row half, 32-col quarter
    const int r4 = lane & 15, kg = lane >> 4;
    const int slot = kg ^ ((r4 >> 1) & 3);
    const int fA = (wm * 64 + r4) * 64 + slot * 16;
    const int fB = (wn * 32 + r4) * 64 + slot * 16;

    f32x4 acc[4][2];
#pragma unroll
    for (int i = 0; i < 4; ++i)
#pragma unroll
        for (int j = 0; j < 2; ++j) acc[i][j] = (f32x4){0.f, 0.f, 0.f, 0.f};

    auto issueB = [&](int ks, int bbuf) {
        if (wave >= 4) {
#pragma unroll
            for (int i = 0; i < 4; ++i) {
                __builtin_amdgcn_global_load_lds(
                    (const __attribute__((address_space(1))) uint32_t*)(
                        gsrcB + (size_t)i * 16 * rowbB + (size_t)ks * 64),
                    (__attribute__((address_space(3))) uint32_t*)(
                        lds + bDst + bbuf * 16384 + i * 1024),
                    16, 0, 0);
            }
        }
    };
    auto loadA = [&](int ks, uint4* R) {
#pragma unroll
        for (int i = 0; i < 2; ++i)
            R[i] = *reinterpret_cast<const uint4*>(
                aSrc + (size_t)i * 64 * KC + (size_t)ks * 32);
    };
    auto writeA = [&](const uint4* R, int abuf) {
#pragma unroll
        for (int i = 0; i < 2; ++i) {
            uint32_t hi01 = __builtin_amdgcn_perm(R[i].y, R[i].x, 0x05040100u);
            uint32_t lo01 = __builtin_amdgcn_perm(R[i].y, R[i].x, 0x07060302u);
            uint32_t hi23 = __builtin_amdgcn_perm(R[i].w, R[i].z, 0x05040100u);
            uint32_t lo23 = __builtin_amdgcn_perm(R[i].w, R[i].z, 0x07060302u);
            *reinterpret_cast<uint2*>(lds + abuf * 16384 + aoff + i * 4096) =
                make_uint2(hi01, hi23);
            *reinterpret_cast<uint2*>(lds + abuf * 16384 + 8192 + aoff + i * 4096) =
                make_uint2(lo01, lo23);
        }
    };
    auto compute = [&](int abuf, int bbuf) {
        short8 ah[4], al[4], bh[2], bl[2];
#pragma unroll
        for (int i = 0; i < 4; ++i) {
            ah[i] = *(const short8*)(lds + abuf * 16384 + fA + i * 1024);
            al[i] = *(const short8*)(lds + abuf * 16384 + 8192 + fA + i * 1024);
        }
#pragma unroll
        for (int j = 0; j < 2; ++j) {
            bh[j] = *(const short8*)(lds + 32768 + bbuf * 16384 + fB + j * 1024);
            bl[j] = *(const short8*)(lds + 32768 + bbuf * 16384 + 8192 + fB + j * 1024);
        }
#pragma unroll
        for (int i = 0; i < 4; ++i)
#pragma unroll
            for (int j = 0; j < 2; ++j) {
                acc[i][j] = __builtin_amdgcn_mfma_f32_16x16x32_bf16(
                    ah[i], bh[j], acc[i][j], 0, 0, 0);
                acc[i][j] = __builtin_amdgcn_mfma_f32_16x16x32_bf16(
                    ah[i], bl[j], acc[i][j], 0, 0, 0);
                acc[i][j] = __builtin_amdgcn_mfma_f32_16x16x32_bf16(
                    al[i], bh[j], acc[i][j], 0, 0, 0);
            }
    };
    auto bar = [&]() {
        asm volatile("s_waitcnt lgkmcnt(0)" ::: "memory");
        __builtin_amdgcn_s_barrier();
        __builtin_amdgcn_sched_barrier(0);
    };

    uint4 R0[2], R1[2];
    // prologue: B(0)->Bbuf0, B(1)->Bbuf1; A(0)->R0, A(1)->R1; A(0)->Abuf0
    issueB(0, 0);
    issueB(1, 1);
    loadA(0, R0);
    loadA(1, R1);
    writeA(R0, 0);   // implicit vmcnt wait retires B(0),B(1),A(0)
    bar();

    int cB = 0;  // B-buf of tile s (s even at loop top)
    for (int s = 0; s + 3 < KSTEPS; s += 2) {
        int cB1 = cB + 1; if (cB1 == 3) cB1 = 0;
        int cB2 = cB1 + 1; if (cB2 == 3) cB2 = 0;
        // phase s (even, abuf 0)
        issueB(s + 2, cB2);
        loadA(s + 2, R0);
        compute(0, cB);
        writeA(R1, 1);   // A(s+1) -> abuf1; retires B(s+1)+A(s+1)
        bar();
        // phase s+1 (odd, abuf 1)
        issueB(s + 3, cB);
        loadA(s + 3, R1);
        compute(1, cB1);
        writeA(R0, 0);   // A(s+2) -> abuf0; retires B(s+2)+A(s+2)
        bar();
        cB = cB2;
    }
    int cB1 = cB + 1; if (cB1 == 3) cB1 = 0;
    // phase KSTEPS-2 (even)
    compute(0, cB);
    writeA(R1, 1);       // A(KSTEPS-1) -> abuf1; retires B(KSTEPS-1)
    bar();
    // phase KSTEPS-1 (odd)
    compute(1, cB1);

    // epilogue: C/D layout col=lane&15, row=(lane>>4)*4+reg
#pragma unroll
    for (int i = 0; i < 4; ++i)
#pragma unroll
        for (int j = 0; j < 2; ++j)
#pragma unroll
            for (int r = 0; r < 4; ++r) {
                int row = m0 + wm * 64 + i * 16 + kg * 4 + r;
                int col = n0 + wn * 32 + j * 16 + r4;
                C[(size_t)row * NC + col] = acc[i][j][r];
            }
}

extern "C" void kernel_launch(void* const* d_in, const int* in_sizes, int n_in,
                              void* d_out, int out_size, void* d_ws,
                              size_t ws_size, hipStream_t stream) {
    const float* inputs = (const float*)d_in[0];  // [500,32,512]
    const float* W1 = (const float*)d_in[1];      // [1024,512]
    const float* W2 = (const float*)d_in[2];      // [512,1024]
    float* out = (float*)d_out;                   // [500,32,512]
    char* ws = (char*)d_ws;

    // workspace (bytes):
    //  region A [0, 65,536,000): s0 packed u32 (32.77MB); later s1 packed (65.54MB)
    //  region B [65,536,000, 131,072,000): x1 f32 (65.54MB); later x2 f32
    //  weights  [131,072,000, 135,266,304): w1h w1l w2h w2l (1MB each)
    uint32_t* s0 = (uint32_t*)ws;
    uint32_t* s1 = (uint32_t*)ws;             // s0 dead after gemm1
    float*    x1 = (float*)(ws + 65536000);
    float*    x2 = (float*)(ws + 65536000);   // x1 dead after scan1
    ushort_t* w1h = (ushort_t*)(ws + 131072000);
    ushort_t* w1l = (ushort_t*)(ws + 132120576);
    ushort_t* w2h = (ushort_t*)(ws + 133169152);
    ushort_t* w2l = (ushort_t*)(ws + 134217728);

    // 1) layer-0 recurrence -> packed sigma, fused with weight split
    scan0_wsplit<<<256 + 8192, 64, 0, stream>>>(inputs, s0, W1, W2,
                                                w1h, w1l, w2h, w2l);
    // 2) X1 = S0 @ (20*W1)^T -> f32 [16000,1024]
    gemm_x3<8, N0><<<1000, 512, 0, stream>>>(s0, w1h, w1l, x1);
    // 3) layer-1 recurrence -> packed sigma
    scan_mid<N1><<<512, 64, 0, stream>>>(x1, s1);
    // 4) X2 = S1 @ (20*W2)^T -> f32 [16000,512]
    gemm_x3<4, N1><<<500, 512, 0, stream>>>(s1, w2h, w2l, x2);
    // 5) layer-2 recurrence -> spikes (20*sigma) -> out
    scan_last<<<256, 64, 0, stream>>>(x2, out);
}